// Round 5
// baseline (237.087 us; speedup 1.0000x reference)
//
#include <hip/hip_runtime.h>
#include <hip/hip_fp16.h>

// Problem constants (from reference)
#define BB 16
#define HH 299
#define WW 299
#define KK 8
#define NPOINTS 200000
#define HWPIX (HH * WW)        // 89401
#define NPIX (BB * HWPIX)      // 1430416
#define PPT 2                  // pixels per thread (16 gathers in flight)
#define TPB 256
#define SPAN (TPB * PPT)

typedef float f4 __attribute__((ext_vector_type(4)));
typedef unsigned int u2 __attribute__((ext_vector_type(2)));

// r0-r4 established: ~85-90 us invariant across (waves x window x L1-bypass)
// -> divergent-gather service cap ~0.22-0.25 lines/cy/CU. This round tests
// bytes-vs-transactions: f16 table halves gather payload (16B->8B) and
// shrinks the table 3.2MB->1.6MB (comfortable XCD-L2 residency vs streaming
// pollution). Gathers keep sc0 (L1 bypass won 5% in r4).

__global__ __launch_bounds__(TPB) void convert_kernel(
    const f4* __restrict__ spatial, u2* __restrict__ tab)
{
    int i = blockIdx.x * TPB + threadIdx.x;
    if (i < NPOINTS) {
        f4 v = spatial[i];
        __half2 a = __floats2half2_rn(v.x, v.y);
        __half2 b = __floats2half2_rn(v.z, v.w);
        u2 r;
        r.x = *reinterpret_cast<unsigned int*>(&a);
        r.y = *reinterpret_cast<unsigned int*>(&b);
        tab[i] = r;
    }
}

__global__ __launch_bounds__(TPB, 4) void gauss_net_kernel_h(
    const u2* __restrict__ tab,      // (N_POINTS) f16x4
    const f4* __restrict__ wi4,      // (B, 2, H, W, K) viewed as f4
    const f4* __restrict__ ori,      // (B, H, W, 4)
    float* __restrict__ out)
{
    const int tbase = blockIdx.x * SPAN + threadIdx.x;

    // Output layout (flat float offsets)
    f4*    out_x    = (f4*)out;
    f4*    out_rgba = out_x + NPIX;
    float* out_cla  = (float*)(out_rgba + NPIX);
    f4*    out_ori  = (f4*)(out_cla + (size_t)BB * 3 * HWPIX);
    float* out_ocla = (float*)(out_ori + NPIX);

    int  p[PPT], bidx[PPT], rem[PPT];
    bool act[PPT];
    f4   w0[PPT], w1[PPT], i0[PPT], i1[PPT], o[PPT];

    // Phase 1: issue ALL streaming loads (weights, indices, ori) — nt, read-once
#pragma unroll
    for (int u = 0; u < PPT; ++u) {
        p[u]   = tbase + u * TPB;
        act[u] = (p[u] < NPIX);
        int pc = act[u] ? p[u] : 0;
        bidx[u] = pc / HWPIX;
        rem[u]  = pc - bidx[u] * HWPIX;
        size_t wb = ((size_t)(2 * bidx[u]) * HWPIX + rem[u]) * 2;  // f4 units
        size_t ib = wb + (size_t)HWPIX * 2;
        w0[u] = __builtin_nontemporal_load(wi4 + wb);
        w1[u] = __builtin_nontemporal_load(wi4 + wb + 1);
        i0[u] = __builtin_nontemporal_load(wi4 + ib);
        i1[u] = __builtin_nontemporal_load(wi4 + ib + 1);
        o[u]  = __builtin_nontemporal_load(ori + pc);
    }

    // Phase 2: issue ALL gathers with L1 bypass (sc0) — random 8B, L2-resident
    // f16 table. All 16 issued before any consumption.
    u2 g[PPT][KK];
#pragma unroll
    for (int u = 0; u < PPT; ++u) {
        int id[KK] = { (int)i0[u].x, (int)i0[u].y, (int)i0[u].z, (int)i0[u].w,
                       (int)i1[u].x, (int)i1[u].y, (int)i1[u].z, (int)i1[u].w };
#pragma unroll
        for (int k = 0; k < KK; ++k) {
            const u2* ap = tab + id[k];
            asm volatile("global_load_dwordx2 %0, %1, off sc0"
                         : "=v"(g[u][k]) : "v"(ap));
        }
    }
    // Drain our asm loads, then fence the scheduler so no consumer is hoisted
    // above the waitcnt (rule: inline-asm waitcnt needs a sched_barrier after).
    asm volatile("s_waitcnt vmcnt(0)" ::: "memory");
    __builtin_amdgcn_sched_barrier(0);

    // Phase 3: reduce + epilogue + nt stores
#pragma unroll
    for (int u = 0; u < PPT; ++u) {
        if (!act[u]) continue;
        float wt[KK] = { w0[u].x, w0[u].y, w0[u].z, w0[u].w,
                         w1[u].x, w1[u].y, w1[u].z, w1[u].w };
        f4 acc = (f4){0.f, 0.f, 0.f, 0.f};
#pragma unroll
        for (int k = 0; k < KK; ++k) {
            union { unsigned int u32; __half2 h; } c0, c1;
            c0.u32 = g[u][k].x;
            c1.u32 = g[u][k].y;
            float2 xy = __half22float2(c0.h);
            float2 zw = __half22float2(c1.h);
            acc.x = fmaf(xy.x, wt[k], acc.x);
            acc.y = fmaf(xy.y, wt[k], acc.y);
            acc.z = fmaf(zw.x, wt[k], acc.z);
            acc.w = fmaf(zw.y, wt[k], acc.w);
        }

        f4 ov = o[u];
        float alpha = acc.w * (1.0f / 255.0f);
        float r  = fmaf(acc.x, alpha, ov.x);
        float gr = fmaf(acc.y, alpha, ov.y);
        float bl = fmaf(acc.z, alpha, ov.z);
        bool oa_pos = (ov.w > 0.0f);
        if (!oa_pos) { r = 0.f; gr = 0.f; bl = 0.f; }

        float cr = fminf(fmaxf(r,  0.f), 255.f);
        float cg = fminf(fmaxf(gr, 0.f), 255.f);
        float cb = fminf(fmaxf(bl, 0.f), 255.f);
        float ca = fminf(fmaxf(ov.w, 0.f), 255.f);

        __builtin_nontemporal_store(acc, out_x + p[u]);
        __builtin_nontemporal_store((f4){cr, cg, cb, ca}, out_rgba + p[u]);
        __builtin_nontemporal_store(ov, out_ori + p[u]);

        size_t cbase = (size_t)bidx[u] * 3 * HWPIX + rem[u];
        bool ca_pos = (ca > 0.0f);
        __builtin_nontemporal_store(ca_pos ? cr : 255.0f, out_cla + cbase);
        __builtin_nontemporal_store(ca_pos ? cg : 255.0f, out_cla + cbase + HWPIX);
        __builtin_nontemporal_store(ca_pos ? cb : 255.0f, out_cla + cbase + 2 * HWPIX);

        __builtin_nontemporal_store(oa_pos ? ov.x : 255.0f, out_ocla + cbase);
        __builtin_nontemporal_store(oa_pos ? ov.y : 255.0f, out_ocla + cbase + HWPIX);
        __builtin_nontemporal_store(oa_pos ? ov.z : 255.0f, out_ocla + cbase + 2 * HWPIX);
    }
}

// ---- f32 fallback (r4 kernel, bit-identical to current best) ----
__global__ __launch_bounds__(TPB, 4) void gauss_net_kernel_f(
    const f4* __restrict__ spatial,
    const f4* __restrict__ wi4,
    const f4* __restrict__ ori,
    float* __restrict__ out)
{
    const int tbase = blockIdx.x * SPAN + threadIdx.x;

    f4*    out_x    = (f4*)out;
    f4*    out_rgba = out_x + NPIX;
    float* out_cla  = (float*)(out_rgba + NPIX);
    f4*    out_ori  = (f4*)(out_cla + (size_t)BB * 3 * HWPIX);
    float* out_ocla = (float*)(out_ori + NPIX);

    int  p[PPT], bidx[PPT], rem[PPT];
    bool act[PPT];
    f4   w0[PPT], w1[PPT], i0[PPT], i1[PPT], o[PPT];

#pragma unroll
    for (int u = 0; u < PPT; ++u) {
        p[u]   = tbase + u * TPB;
        act[u] = (p[u] < NPIX);
        int pc = act[u] ? p[u] : 0;
        bidx[u] = pc / HWPIX;
        rem[u]  = pc - bidx[u] * HWPIX;
        size_t wb = ((size_t)(2 * bidx[u]) * HWPIX + rem[u]) * 2;
        size_t ib = wb + (size_t)HWPIX * 2;
        w0[u] = __builtin_nontemporal_load(wi4 + wb);
        w1[u] = __builtin_nontemporal_load(wi4 + wb + 1);
        i0[u] = __builtin_nontemporal_load(wi4 + ib);
        i1[u] = __builtin_nontemporal_load(wi4 + ib + 1);
        o[u]  = __builtin_nontemporal_load(ori + pc);
    }

    f4 g[PPT][KK];
#pragma unroll
    for (int u = 0; u < PPT; ++u) {
        int id[KK] = { (int)i0[u].x, (int)i0[u].y, (int)i0[u].z, (int)i0[u].w,
                       (int)i1[u].x, (int)i1[u].y, (int)i1[u].z, (int)i1[u].w };
#pragma unroll
        for (int k = 0; k < KK; ++k) {
            const f4* ap = spatial + id[k];
            asm volatile("global_load_dwordx4 %0, %1, off sc0"
                         : "=v"(g[u][k]) : "v"(ap));
        }
    }
    asm volatile("s_waitcnt vmcnt(0)" ::: "memory");
    __builtin_amdgcn_sched_barrier(0);

#pragma unroll
    for (int u = 0; u < PPT; ++u) {
        if (!act[u]) continue;
        float wt[KK] = { w0[u].x, w0[u].y, w0[u].z, w0[u].w,
                         w1[u].x, w1[u].y, w1[u].z, w1[u].w };
        f4 acc = (f4){0.f, 0.f, 0.f, 0.f};
#pragma unroll
        for (int k = 0; k < KK; ++k) acc += g[u][k] * wt[k];

        f4 ov = o[u];
        float alpha = acc.w * (1.0f / 255.0f);
        float r  = fmaf(acc.x, alpha, ov.x);
        float gr = fmaf(acc.y, alpha, ov.y);
        float bl = fmaf(acc.z, alpha, ov.z);
        bool oa_pos = (ov.w > 0.0f);
        if (!oa_pos) { r = 0.f; gr = 0.f; bl = 0.f; }

        float cr = fminf(fmaxf(r,  0.f), 255.f);
        float cg = fminf(fmaxf(gr, 0.f), 255.f);
        float cb = fminf(fmaxf(bl, 0.f), 255.f);
        float ca = fminf(fmaxf(ov.w, 0.f), 255.f);

        __builtin_nontemporal_store(acc, out_x + p[u]);
        __builtin_nontemporal_store((f4){cr, cg, cb, ca}, out_rgba + p[u]);
        __builtin_nontemporal_store(ov, out_ori + p[u]);

        size_t cbase = (size_t)bidx[u] * 3 * HWPIX + rem[u];
        bool ca_pos = (ca > 0.0f);
        __builtin_nontemporal_store(ca_pos ? cr : 255.0f, out_cla + cbase);
        __builtin_nontemporal_store(ca_pos ? cg : 255.0f, out_cla + cbase + HWPIX);
        __builtin_nontemporal_store(ca_pos ? cb : 255.0f, out_cla + cbase + 2 * HWPIX);

        __builtin_nontemporal_store(oa_pos ? ov.x : 255.0f, out_ocla + cbase);
        __builtin_nontemporal_store(oa_pos ? ov.y : 255.0f, out_ocla + cbase + HWPIX);
        __builtin_nontemporal_store(oa_pos ? ov.z : 255.0f, out_ocla + cbase + 2 * HWPIX);
    }
}

extern "C" void kernel_launch(void* const* d_in, const int* in_sizes, int n_in,
                              void* d_out, int out_size, void* d_ws, size_t ws_size,
                              hipStream_t stream) {
    const f4* spatial = (const f4*)d_in[0];
    const f4* wi4     = (const f4*)d_in[1];
    const f4* ori     = (const f4*)d_in[2];
    float* out = (float*)d_out;

    int blocks = (NPIX + SPAN - 1) / SPAN;
    if (ws_size >= (size_t)NPOINTS * 8) {
        u2* tab = (u2*)d_ws;
        int cblocks = (NPOINTS + TPB - 1) / TPB;
        convert_kernel<<<cblocks, TPB, 0, stream>>>(spatial, tab);
        gauss_net_kernel_h<<<blocks, TPB, 0, stream>>>(tab, wi4, ori, out);
    } else {
        gauss_net_kernel_f<<<blocks, TPB, 0, stream>>>(spatial, wi4, ori, out);
    }
}

// Round 6
// 227.813 us; speedup vs baseline: 1.0407x; 1.0407x over previous
//
#include <hip/hip_runtime.h>

// Problem constants (from reference)
#define BB 16
#define HH 299
#define WW 299
#define KK 8
#define HWPIX (HH * WW)        // 89401
#define NPIX (BB * HWPIX)      // 1430416
#define PPT 2                  // pixels per thread (16 gathers in flight)
#define TPB 256
#define SPAN (TPB * PPT)

typedef float f4 __attribute__((ext_vector_type(4)));

// FINAL (r4 revert): r0-r5 established the divergent-gather service wall:
// 11.44M random 16B gathers / 256 CU at ~4.3 cy/transaction ≈ 80 us floor,
// invariant to occupancy (5.4-13.8 waves/CU), per-wave window (9-32),
// L1 allocate/bypass, payload (16B/8B), and table residency (3.2/1.6 MB).
// Streaming HBM traffic (~180 MB ≈ 29 us) hides fully underneath.
// sc0 L1-bypass on gathers is the one retained micro-win (-5%, r4).
__global__ __launch_bounds__(TPB, 4) void gauss_net_kernel(
    const f4* __restrict__ spatial,  // (N_POINTS, 4)
    const f4* __restrict__ wi4,      // (B, 2, H, W, K) viewed as f4
    const f4* __restrict__ ori,      // (B, H, W, 4)
    float* __restrict__ out)
{
    const int tbase = blockIdx.x * SPAN + threadIdx.x;

    // Output layout (flat float offsets)
    f4*    out_x    = (f4*)out;
    f4*    out_rgba = out_x + NPIX;
    float* out_cla  = (float*)(out_rgba + NPIX);
    f4*    out_ori  = (f4*)(out_cla + (size_t)BB * 3 * HWPIX);
    float* out_ocla = (float*)(out_ori + NPIX);

    int  p[PPT], bidx[PPT], rem[PPT];
    bool act[PPT];
    f4   w0[PPT], w1[PPT], i0[PPT], i1[PPT], o[PPT];

    // Phase 1: issue ALL streaming loads (weights, indices, ori) — nt, read-once
#pragma unroll
    for (int u = 0; u < PPT; ++u) {
        p[u]   = tbase + u * TPB;
        act[u] = (p[u] < NPIX);
        int pc = act[u] ? p[u] : 0;
        bidx[u] = pc / HWPIX;
        rem[u]  = pc - bidx[u] * HWPIX;
        size_t wb = ((size_t)(2 * bidx[u]) * HWPIX + rem[u]) * 2;  // f4 units
        size_t ib = wb + (size_t)HWPIX * 2;
        w0[u] = __builtin_nontemporal_load(wi4 + wb);
        w1[u] = __builtin_nontemporal_load(wi4 + wb + 1);
        i0[u] = __builtin_nontemporal_load(wi4 + ib);
        i1[u] = __builtin_nontemporal_load(wi4 + ib + 1);
        o[u]  = __builtin_nontemporal_load(ori + pc);
    }

    // Phase 2: issue ALL gathers with L1 bypass (sc0) — random 16B, L2-resident
    // table. All 16 issued before any consumption.
    f4 g[PPT][KK];
#pragma unroll
    for (int u = 0; u < PPT; ++u) {
        int id[KK] = { (int)i0[u].x, (int)i0[u].y, (int)i0[u].z, (int)i0[u].w,
                       (int)i1[u].x, (int)i1[u].y, (int)i1[u].z, (int)i1[u].w };
#pragma unroll
        for (int k = 0; k < KK; ++k) {
            const f4* ap = spatial + id[k];
            asm volatile("global_load_dwordx4 %0, %1, off sc0"
                         : "=v"(g[u][k]) : "v"(ap));
        }
    }
    // Drain our asm loads, then fence the scheduler so no consumer is hoisted
    // above the waitcnt (rule: inline-asm waitcnt needs a sched_barrier after).
    asm volatile("s_waitcnt vmcnt(0)" ::: "memory");
    __builtin_amdgcn_sched_barrier(0);

    // Phase 3: reduce + epilogue + nt stores
#pragma unroll
    for (int u = 0; u < PPT; ++u) {
        if (!act[u]) continue;
        float wt[KK] = { w0[u].x, w0[u].y, w0[u].z, w0[u].w,
                         w1[u].x, w1[u].y, w1[u].z, w1[u].w };
        f4 acc = (f4){0.f, 0.f, 0.f, 0.f};
#pragma unroll
        for (int k = 0; k < KK; ++k) acc += g[u][k] * wt[k];

        f4 ov = o[u];
        float alpha = acc.w * (1.0f / 255.0f);
        float r  = fmaf(acc.x, alpha, ov.x);
        float gr = fmaf(acc.y, alpha, ov.y);
        float bl = fmaf(acc.z, alpha, ov.z);
        bool oa_pos = (ov.w > 0.0f);
        if (!oa_pos) { r = 0.f; gr = 0.f; bl = 0.f; }

        float cr = fminf(fmaxf(r,  0.f), 255.f);
        float cg = fminf(fmaxf(gr, 0.f), 255.f);
        float cb = fminf(fmaxf(bl, 0.f), 255.f);
        float ca = fminf(fmaxf(ov.w, 0.f), 255.f);

        __builtin_nontemporal_store(acc, out_x + p[u]);
        __builtin_nontemporal_store((f4){cr, cg, cb, ca}, out_rgba + p[u]);
        __builtin_nontemporal_store(ov, out_ori + p[u]);

        size_t cbase = (size_t)bidx[u] * 3 * HWPIX + rem[u];
        bool ca_pos = (ca > 0.0f);
        __builtin_nontemporal_store(ca_pos ? cr : 255.0f, out_cla + cbase);
        __builtin_nontemporal_store(ca_pos ? cg : 255.0f, out_cla + cbase + HWPIX);
        __builtin_nontemporal_store(ca_pos ? cb : 255.0f, out_cla + cbase + 2 * HWPIX);

        __builtin_nontemporal_store(oa_pos ? ov.x : 255.0f, out_ocla + cbase);
        __builtin_nontemporal_store(oa_pos ? ov.y : 255.0f, out_ocla + cbase + HWPIX);
        __builtin_nontemporal_store(oa_pos ? ov.z : 255.0f, out_ocla + cbase + 2 * HWPIX);
    }
}

extern "C" void kernel_launch(void* const* d_in, const int* in_sizes, int n_in,
                              void* d_out, int out_size, void* d_ws, size_t ws_size,
                              hipStream_t stream) {
    const f4* spatial = (const f4*)d_in[0];
    const f4* wi4     = (const f4*)d_in[1];
    const f4* ori     = (const f4*)d_in[2];
    float* out = (float*)d_out;

    int blocks = (NPIX + SPAN - 1) / SPAN;
    gauss_net_kernel<<<blocks, TPB, 0, stream>>>(spatial, wi4, ori, out);
}